// Round 10
// baseline (160.410 us; speedup 1.0000x reference)
//
#include <hip/hip_runtime.h>
#include <cstdint>

// CamPoseNet: bit-faithful JAX threefry replication (validated rounds 1-4).
// Round 15: compiler-native packed-FP32. R12's pk-asm failed on register
// marshalling + scheduling opacity; this round uses ext_vector_type(2)
// arithmetic so LLVM selects v_pk_mul_f32/v_pk_add_f32 itself (gfx90a+
// hasPackedFP32Ops) and allocates pairs globally. Bit-exactness: each vector
// lane is the same IEEE-RN op in the same order as the validated scalar DAG;
// #pragma clang fp contract(off) in every vectorized scope blocks hipcc's
// default -ffp-contract=fast from fusing mul+add into pk_fma; vector fsub
// lowers to pk_add with neg modifier (exact). Vectorized (pairs of
// independent streams only): log5 poly+tail, erfinv fast-path poly, y-scale,
// {s1v,s2v} accumulation. Int threefry is un-packable (no pk_add_u32).
// Structure/geometry identical to R14 (fused E^T epilogue, erfinv ballot
// fast path, GRID=512, float4 rc packing, NG=16 x GW=4 gang tail).
// All scalar float ops on the accept-decision path keep __f*_rn intrinsics.
// Do not alter any arithmetic.

#define DEVI __device__ __forceinline__
#define MAXT 96
#define GRID 512
#define NT 256
#define CMAX 2048
#define GANGA 56
#define NG 16
#define GW 4

typedef float f32x2 __attribute__((ext_vector_type(2)));

DEVI uint32_t rotl32(uint32_t v, int s) { return (v << s) | (v >> (32 - s)); }

// Threefry-2x32, 20 rounds (jax._src.prng.threefry2x32) - scalar form,
// used only by the chain producer.
DEVI void tf2x32(uint32_t k0, uint32_t k1, uint32_t x0, uint32_t x1,
                 uint32_t& o0, uint32_t& o1) {
  const uint32_t kx = k0 ^ k1 ^ 0x1BD11BDAu;
  x0 += k0; x1 += k1;
#define TFR(r) x0 += x1; x1 = rotl32(x1, (r)); x1 ^= x0;
  TFR(13) TFR(15) TFR(26) TFR(6)
  x0 += k1; x1 += kx + 1u;
  TFR(17) TFR(29) TFR(16) TFR(24)
  x0 += kx; x1 += k0 + 2u;
  TFR(13) TFR(15) TFR(26) TFR(6)
  x0 += k0; x1 += k1 + 3u;
  TFR(17) TFR(29) TFR(16) TFR(24)
  x0 += k1; x1 += kx + 4u;
  TFR(13) TFR(15) TFR(26) TFR(6)
  x0 += kx; x1 += k0 + 5u;
#undef TFR
  o0 = x0; o1 = x1;
}

// 5-way interleaved threefry: streams 0-3 use key (ck.x,ck.y) with counters
// base+j; stream 4 uses key (ck.z,ck.w) with counter ctr. Identical per-stream
// op sequence to tf2x32 (only instruction interleaving differs).
DEVI void tf_round5(uint32_t x0[5], uint32_t x1[5], int rr) {
#pragma unroll
  for (int j = 0; j < 5; ++j) {
    x0[j] += x1[j];
    x1[j] = rotl32(x1[j], rr);
    x1[j] ^= x0[j];
  }
}
DEVI void tf_inj5(uint32_t x0[5], uint32_t x1[5],
                  const uint32_t* sa, const uint32_t* sb, uint32_t add) {
#pragma unroll
  for (int j = 0; j < 5; ++j) { x0[j] += sa[j]; x1[j] += sb[j] + add; }
}

DEVI float u01_from_bits(uint32_t bits) {
  return __fsub_rn(__uint_as_float(0x3f800000u | (bits >> 9)), 1.0f);
}

DEVI void trial5(uint4 ck, uint32_t base, uint32_t ctr, float u[5]) {
  uint32_t s0[5], s1[5], s2k[5], x0[5], x1[5];
#pragma unroll
  for (int j = 0; j < 5; ++j) {
    uint32_t k0 = (j < 4) ? ck.x : ck.z;
    uint32_t k1 = (j < 4) ? ck.y : ck.w;
    s0[j] = k0; s1[j] = k1; s2k[j] = k0 ^ k1 ^ 0x1BD11BDAu;
    uint32_t c = (j < 4) ? (base + (uint32_t)j) : ctr;
    x0[j] = k0;        // 0 + k0
    x1[j] = c + k1;    // counter + k1
  }
  tf_round5(x0, x1, 13); tf_round5(x0, x1, 15);
  tf_round5(x0, x1, 26); tf_round5(x0, x1, 6);
  tf_inj5(x0, x1, s1, s2k, 1u);
  tf_round5(x0, x1, 17); tf_round5(x0, x1, 29);
  tf_round5(x0, x1, 16); tf_round5(x0, x1, 24);
  tf_inj5(x0, x1, s2k, s0, 2u);
  tf_round5(x0, x1, 13); tf_round5(x0, x1, 15);
  tf_round5(x0, x1, 26); tf_round5(x0, x1, 6);
  tf_inj5(x0, x1, s0, s1, 3u);
  tf_round5(x0, x1, 17); tf_round5(x0, x1, 29);
  tf_round5(x0, x1, 16); tf_round5(x0, x1, 24);
  tf_inj5(x0, x1, s1, s2k, 4u);
  tf_round5(x0, x1, 13); tf_round5(x0, x1, 15);
  tf_round5(x0, x1, 26); tf_round5(x0, x1, 6);
  tf_inj5(x0, x1, s2k, s0, 5u);
#pragma unroll
  for (int j = 0; j < 5; ++j) u[j] = u01_from_bits(x0[j] ^ x1[j]);
}

// Scalar XLA:CPU Cephes-style f32 log (K=1, for log(s2v)).
template <int K>
DEVI void xla_logf_pos_k(const float* xf, float* out) {
  float e[K], m[K], z[K], y[K];
#pragma unroll
  for (int j = 0; j < K; ++j) {
    uint32_t bits = __float_as_uint(xf[j]);
    e[j] = (float)((int)(bits >> 23) - 126);
    m[j] = __uint_as_float((bits & 0x007fffffu) | 0x3f000000u);  // [0.5,1)
    bool mc = m[j] < 0.70710678118654752440f;
    float e_lo = __fsub_rn(e[j], 1.0f);
    float m_lo = __fadd_rn(__fsub_rn(m[j], 1.0f), m[j]);
    float m_hi = __fsub_rn(m[j], 1.0f);
    e[j] = mc ? e_lo : e[j];
    m[j] = mc ? m_lo : m_hi;
    z[j] = __fmul_rn(m[j], m[j]);
    y[j] = 7.0376836292e-2f;
  }
  const float LC[8] = {-1.1514610310e-1f,  1.1676998740e-1f,
                       -1.2420140846e-1f,  1.4249322787e-1f,
                       -1.6668057665e-1f,  2.0000714765e-1f,
                       -2.4999993993e-1f,  3.3333331174e-1f};
#pragma unroll
  for (int s = 0; s < 8; ++s)
#pragma unroll
    for (int j = 0; j < K; ++j)
      y[j] = __fadd_rn(__fmul_rn(y[j], m[j]), LC[s]);
#pragma unroll
  for (int j = 0; j < K; ++j) {
    float t = __fmul_rn(__fmul_rn(y[j], m[j]), z[j]);
    t = __fadd_rn(t, __fmul_rn(e[j], -2.12194440e-4f));
    t = __fsub_rn(t, __fmul_rn(z[j], 0.5f));
    float r = __fadd_rn(m[j], t);
    out[j] = __fadd_rn(r, __fmul_rn(e[j], 0.693359375f));
  }
}

// 5-stream XLA log: scalar head (bit ops + selects, __f*_rn as validated),
// vector poly+tail on stream pairs {0,1},{2,3} + scalar stream 4. Each
// vector lane = identical IEEE-RN op order to the scalar DAG; contract(off)
// forbids mul+add fusion. Bit-exact.
DEVI void xla_logf_pos5_v(const float* xf, float* out) {
  float e[5], m[5];
#pragma unroll
  for (int j = 0; j < 5; ++j) {
    uint32_t bits = __float_as_uint(xf[j]);
    e[j] = (float)((int)(bits >> 23) - 126);
    m[j] = __uint_as_float((bits & 0x007fffffu) | 0x3f000000u);  // [0.5,1)
    bool mc = m[j] < 0.70710678118654752440f;
    float e_lo = __fsub_rn(e[j], 1.0f);
    float m_lo = __fadd_rn(__fsub_rn(m[j], 1.0f), m[j]);
    float m_hi = __fsub_rn(m[j], 1.0f);
    e[j] = mc ? e_lo : e[j];
    m[j] = mc ? m_lo : m_hi;
  }
  const float LC[8] = {-1.1514610310e-1f,  1.1676998740e-1f,
                       -1.2420140846e-1f,  1.4249322787e-1f,
                       -1.6668057665e-1f,  2.0000714765e-1f,
                       -2.4999993993e-1f,  3.3333331174e-1f};
  float y4, z4;
  f32x2 r01, r23;
  {
#pragma clang fp contract(off)
    f32x2 m01 = {m[0], m[1]}, m23 = {m[2], m[3]};
    f32x2 e01 = {e[0], e[1]}, e23 = {e[2], e[3]};
    f32x2 z01 = m01 * m01, z23 = m23 * m23;
    z4 = __fmul_rn(m[4], m[4]);
    f32x2 y01 = {7.0376836292e-2f, 7.0376836292e-2f};
    f32x2 y23 = y01;
    y4 = 7.0376836292e-2f;
#pragma unroll
    for (int s = 0; s < 8; ++s) {
      f32x2 lc = {LC[s], LC[s]};
      y01 = y01 * m01 + lc;          // pk_mul then pk_add (no contraction)
      y23 = y23 * m23 + lc;
      y4 = __fadd_rn(__fmul_rn(y4, m[4]), LC[s]);
    }
    const f32x2 c1 = {-2.12194440e-4f, -2.12194440e-4f};
    const f32x2 hf = {0.5f, 0.5f};
    const f32x2 c2 = {0.693359375f, 0.693359375f};
    f32x2 t01 = (y01 * m01) * z01;
    f32x2 t23 = (y23 * m23) * z23;
    t01 = t01 + e01 * c1;
    t23 = t23 + e23 * c1;
    t01 = t01 - z01 * hf;            // fsub -> pk_add(neg), bit-exact
    t23 = t23 - z23 * hf;
    r01 = m01 + t01;
    r23 = m23 + t23;
    r01 = r01 + e01 * c2;
    r23 = r23 + e23 * c2;
  }
  out[0] = r01[0]; out[1] = r01[1]; out[2] = r23[0]; out[3] = r23[1];
  float t4 = __fmul_rn(__fmul_rn(y4, m[4]), z4);
  t4 = __fadd_rn(t4, __fmul_rn(e[4], -2.12194440e-4f));
  t4 = __fsub_rn(t4, __fmul_rn(z4, 0.5f));
  out[4] = __fadd_rn(__fadd_rn(m[4], t4), __fmul_rn(e[4], 0.693359375f));
}

// 4-way XLA ErfInv32 + uniform's log as 5th stream. Wave-uniform fast path
// (P~0.42): all streams on w<5 -> no selects/sqrt, poly vectorized in pairs.
// Slow path = original scalar select code. Identical per-lane DAG either way.
DEVI void xla_erfinv4_logu(const float* xin, float uu, float* res,
                           float& lg_uu) {
  float v[4], vp1[5], big[5], w[4];
  bool c[4];
#pragma unroll
  for (int j = 0; j < 4; ++j) {
    v[j] = -__fmul_rn(xin[j], xin[j]);
    vp1[j] = __fadd_rn(v[j], 1.0f);
  }
  vp1[4] = uu;                      // independent 5th log stream
  xla_logf_pos5_v(vp1, big);
  lg_uu = big[4];
#pragma unroll
  for (int j = 0; j < 4; ++j) {
    float small = __fmul_rn(__fadd_rn(__fmul_rn(-0.5f, v[j]), 1.0f), v[j]);
    float l1p = (fabsf(v[j]) < 1e-4f) ? small : big[j];
    w[j] = -l1p;
    c[j] = (w[j] < 5.0f);
  }
  const float CF[8] = { 3.43273939e-07f, -3.5233877e-06f, -4.39150654e-06f,
                        0.00021858087f,  -0.00125372503f, -0.00417768164f,
                        0.246640727f,     1.50140941f};
  const float CR[8] = { 0.000100950558f,  0.00134934322f, -0.00367342844f,
                        0.00573950773f,  -0.0076224613f,   0.00943887047f,
                        1.00167406f,      2.83297682f};
  bool slow = !(c[0] && c[1] && c[2] && c[3]);
  if (__ballot(slow) == 0ull) {
    // fast: all streams take w<5 -> q=w-2.5, CF-only chain, vector pairs.
    f32x2 r01, r23;
    {
#pragma clang fp contract(off)
      f32x2 w01 = {w[0], w[1]}, w23 = {w[2], w[3]};
      const f32x2 t5 = {2.5f, 2.5f};
      f32x2 q01 = w01 - t5, q23 = w23 - t5;
      f32x2 p01 = {2.81022636e-08f, 2.81022636e-08f};
      f32x2 p23 = p01;
#pragma unroll
      for (int s = 0; s < 8; ++s) {
        f32x2 cf = {CF[s], CF[s]};
        p01 = p01 * q01 + cf;
        p23 = p23 * q23 + cf;
      }
      f32x2 x01 = {xin[0], xin[1]}, x23 = {xin[2], xin[3]};
      r01 = p01 * x01;
      r23 = p23 * x23;
    }
    res[0] = r01[0]; res[1] = r01[1]; res[2] = r23[0]; res[3] = r23[1];
  } else {
    // slow: original scalar coefficient-select form.
    float q[4], p[4];
#pragma unroll
    for (int j = 0; j < 4; ++j) {
      float qc = __fsub_rn(w[j], 2.5f);
      float qr = __fsub_rn(sqrtf(w[j]), 3.0f);
      q[j] = c[j] ? qc : qr;
      p[j] = c[j] ? 2.81022636e-08f : -0.000200214257f;
    }
#pragma unroll
    for (int s = 0; s < 8; ++s)
#pragma unroll
      for (int j = 0; j < 4; ++j)
        p[j] = __fadd_rn(__fmul_rn(p[j], q[j]), c[j] ? CF[s] : CR[s]);
#pragma unroll
    for (int j = 0; j < 4; ++j) res[j] = __fmul_rn(p[j], xin[j]);
  }
}

// One full rejection trial for row r with subkeys ck: pure function of
// (r, ck, row constants). Returns the lu<lr accept test; y out by ref.
// Value DAG identical to the validated R8/R10/R14 loop body (shared by
// normal + gang paths -> bit-exact).
DEVI bool trial_eval(uint4 ck, int r,
                     float lam1, float lam2, float lam3,
                     float sgi1, float sgi2, float sgi3,
                     float sig1, float sig2, float sig3,
                     float sgi0, float sig0,
                     float& ry0, float& ry1, float& ry2, float& ry3) {
  const uint32_t base = ((uint32_t)r) * 4u;

  // 5 interleaved threefry streams: 4 normals + 1 uniform
  float u5[5];
  trial5(ck, base, (uint32_t)r, u5);
  float uu = u5[4];

  float xin[4];
#pragma unroll
  for (int j = 0; j < 4; ++j) {
    float x = __fadd_rn(__fmul_rn(u5[j], 2.0f), -0.99999994f);
    xin[j] = fmaxf(-0.99999994f, x);
  }
  float er[4], lg_uu;
  xla_erfinv4_logu(xin, uu, er, lg_uu);   // log(uu) rides the 4-way log

  // y = (sqrt2 * er) * sig, vector pairs (same op order as scalar)
  float y0, y1, y2v, y3;
  {
#pragma clang fp contract(off)
    f32x2 er01 = {er[0], er[1]}, er23 = {er[2], er[3]};
    f32x2 ys01 = (1.41421356237309504880f * er01) * f32x2{sig0, sig1};
    f32x2 ys23 = (1.41421356237309504880f * er23) * f32x2{sig2, sig3};
    y0 = ys01[0]; y1 = ys01[1]; y2v = ys23[0]; y3 = ys23[1];
  }

  // normalize (sequential reduce order)
  float n2 = __fmul_rn(y0, y0);
  n2 = __fadd_rn(n2, __fmul_rn(y1, y1));
  n2 = __fadd_rn(n2, __fmul_rn(y2v, y2v));
  n2 = __fadd_rn(n2, __fmul_rn(y3, y3));
  float nr = sqrtf(n2);
  y0 = __fdiv_rn(y0, nr); y1 = __fdiv_rn(y1, nr);
  y2v = __fdiv_rn(y2v, nr); y3 = __fdiv_rn(y3, nr);

  float s0q = __fmul_rn(y0, y0), s1q = __fmul_rn(y1, y1);
  float s2q = __fmul_rn(y2v, y2v), s3q = __fmul_rn(y3, y3);

  // {s1v, s2v} accumulated as one packed chain (lane0 = s1v DAG, lane1 = s2v)
  float s1v, s2v;
  {
#pragma clang fp contract(off)
    f32x2 sv = f32x2{1e-6f, sgi0} * s0q;
    sv = sv + f32x2{lam1, sgi1} * s1q;
    sv = sv + f32x2{lam2, sgi2} * s2q;
    sv = sv + f32x2{lam3, sgi3} * s3q;
    s1v = sv[0]; s2v = sv[1];
  }

  float lg_s2[1];
  xla_logf_pos_k<1>(&s2v, lg_s2);

  float lr = __fsub_rn(-s1v, 2.7725887298583984f);  // 2*f32(ln 4)
  lr = __fadd_rn(lr, 1.5f);
  lr = __fadd_rn(lr, __fmul_rn(2.0f, lg_s2[0]));

  float lu = (uu > 0.0f) ? lg_uu : -__builtin_inff();

  ry0 = y0; ry1 = y1; ry2 = y2v; ry3 = y3;
  return (lu < lr);
}

// Fused epilogue: qn-normalize + E^T matvec + store. DAG copied verbatim
// from the validated pass-2 loop (bit-exact); executed once per row at its
// accepting trial.
DEVI void store_final(float* __restrict__ out, int r,
                      float qa, float qb, float qc_, float qd,
                      float y0, float y1, float y2v, float y3) {
  float a = qa, b = qb, c = qc_, d = qd;
  float qn2 = __fmul_rn(a, a);
  qn2 = __fadd_rn(qn2, __fmul_rn(b, b));
  qn2 = __fadd_rn(qn2, __fmul_rn(c, c));
  qn2 = __fadd_rn(qn2, __fmul_rn(d, d));
  float qnr = sqrtf(qn2);
  a = __fdiv_rn(a, qnr); b = __fdiv_rn(b, qnr);
  c = __fdiv_rn(c, qnr); d = __fdiv_rn(d, qnr);
  float o0v = __fadd_rn(__fadd_rn(__fadd_rn(__fmul_rn(a, y0), __fmul_rn(b, y1)),
                                  __fmul_rn(c, y2v)), __fmul_rn(d, y3));
  float o1v = __fadd_rn(__fadd_rn(__fadd_rn(__fmul_rn(-b, y0), __fmul_rn(a, y1)),
                                  __fmul_rn(-d, y2v)), __fmul_rn(c, y3));
  float o2v = __fadd_rn(__fadd_rn(__fadd_rn(__fmul_rn(-c, y0), __fmul_rn(d, y1)),
                                  __fmul_rn(a, y2v)), __fmul_rn(-b, y3));
  float o3v = __fadd_rn(__fadd_rn(__fadd_rn(__fmul_rn(d, y0), __fmul_rn(c, y1)),
                                  __fmul_rn(-b, y2v)), __fmul_rn(-a, y3));
  *reinterpret_cast<float4*>(out + (size_t)r * 4) =
      make_float4(o0v, o1v, o2v, o3v);
}

// ---------------------------------------------------------------------------
__global__ __launch_bounds__(256, 2) void campose_kernel(
    const float* __restrict__ q, const float* __restrict__ Z,
    float* __restrict__ out, const int* __restrict__ seedp, int N, int C) {
  __shared__ uint4 chain[MAXT + 1];
  // Packed row constants (bit-exact values; only the load shape changed):
  //   rc4a[i] = {sgi1, sgi2, sgi3, sig1}
  //   rc4b[i] = {sig2, sig3, lam1, lam2}
  //   rc1[i]  = lam3
  __shared__ float4 rc4a[CMAX];
  __shared__ float4 rc4b[CMAX];
  __shared__ float rc1[CMAX];
  __shared__ uint32_t next_row;
  __shared__ uint32_t wm;   // watermark: # of published chain entries

  const int tid = threadIdx.x;
  const int lane = tid & 63;
  const int rbeg = blockIdx.x * C;
  const int rend = min(N, rbeg + C);
  const int crows = rend - rbeg;
  if (tid == 0) { next_row = (uint32_t)(rbeg + 192); wm = 0u; }

  // --- prepass: row constants (dense, high-ILP; values bit-identical to the
  // per-accept recompute they replace) ---
  for (int i = tid; i < crows; i += NT) {
    float z0 = Z[(size_t)(rbeg + i) * 3 + 0];
    float z1 = Z[(size_t)(rbeg + i) * 3 + 1];
    float z2 = Z[(size_t)(rbeg + i) * 3 + 2];
    float l1 = -z0, l2 = -z1, l3 = -z2;
    float g1 = __fadd_rn(1.0f, __fmul_rn(2.0f, l1));
    float g2 = __fadd_rn(1.0f, __fmul_rn(2.0f, l2));
    float g3 = __fadd_rn(1.0f, __fmul_rn(2.0f, l3));
    float s1_ = sqrtf(__fdiv_rn(1.0f, g1));
    float s2_ = sqrtf(__fdiv_rn(1.0f, g2));
    float s3_ = sqrtf(__fdiv_rn(1.0f, g3));
    rc4a[i] = make_float4(g1, g2, g3, s1_);
    rc4b[i] = make_float4(s2_, s3_, l1, l2);
    rc1[i] = l3;
  }
  __syncthreads();

  const int wave = tid >> 6;
  if (wave == 0) {
    // Producer: lanes 0-2 of wave 0 walk the split() chain; publish each
    // entry with a release watermark. Other waves consume concurrently.
    uint32_t ka = 0u, kb = (uint32_t)seedp[0];
    uint32_t x1i = (lane == 2) ? 0u : (uint32_t)(lane + 1);
    for (int t = 0; t < MAXT; ++t) {
      uint32_t o0 = 0u, o1 = 0u;
      if (lane < 3) tf2x32(ka, kb, 0u, x1i, o0, o1);
      uint32_t s1a = __shfl(o0, 0, 64), s1b = __shfl(o1, 0, 64);
      uint32_t s2a = __shfl(o0, 1, 64), s2b = __shfl(o1, 1, 64);
      if (lane == 0) chain[t] = make_uint4(s1a, s1b, s2a, s2b);
      ka = __shfl(o0, 2, 64); kb = __shfl(o1, 2, 64);
      __threadfence_block();
      if (lane == 0) *(volatile uint32_t*)&wm = (uint32_t)(t + 1);
    }
    if (lane == 0) chain[MAXT] = make_uint4(0u, 0u, 0u, 0u);  // prefetch pad
    __threadfence_block();
    if (lane == 0) *(volatile uint32_t*)&wm = (uint32_t)(MAXT + 1);
  }

  const float sgi0 = __fadd_rn(1.0f, __fmul_rn(2.0f, 1e-6f));
  const float sig0 = sqrtf(__fdiv_rn(1.0f, sgi0));

  // --- per-lane row state: current row r + pre-grabbed next row rn ---
  int r, rn;
  if (wave == 0) {
    r  = (int)atomicAdd(&next_row, 1u);   // producer wave joins late; queue
    rn = (int)atomicAdd(&next_row, 1u);   // auto-balances
  } else {
    r  = rbeg + (tid - 64);               // static first 192 rows
    rn = (int)atomicAdd(&next_row, 1u);
  }
  bool have = (r < rend);
  float lam1 = 0, lam2 = 0, lam3 = 0;
  float sgi1 = 1, sgi2 = 1, sgi3 = 1;
  float sig1 = 1, sig2 = 1, sig3 = 1;
  float cq0 = 0, cq1 = 0, cq2 = 0, cq3 = 0;   // current row's q (prefetched)
  float nq0 = 0, nq1 = 0, nq2 = 0, nq3 = 0;   // next row's q (prefetched)
  if (have) {
    int li = r - rbeg;
    float4 A = rc4a[li], B = rc4b[li];
    sgi1 = A.x; sgi2 = A.y; sgi3 = A.z; sig1 = A.w;
    sig2 = B.x; sig3 = B.y; lam1 = B.z; lam2 = B.w;
    lam3 = rc1[li];
    float4 qv = *reinterpret_cast<const float4*>(q + (size_t)r * 4);
    cq0 = qv.x; cq1 = qv.y; cq2 = qv.z; cq3 = qv.w;
  }
  if (rn < rend) {
    float4 qv = *reinterpret_cast<const float4*>(q + (size_t)rn * 4);
    nq0 = qv.x; nq1 = qv.y; nq2 = qv.z; nq3 = qv.w;
  }

  // wait for chain[0]; cache it (reused at every accept)
  uint32_t wml = *(volatile uint32_t*)&wm;
  while (wml < 1u) wml = *(volatile uint32_t*)&wm;
  __threadfence_block();
  const uint4 ck0 = chain[0];
  uint4 ck = ck0;
  int t = 0;

  // --- normal phase: per-lane async rows; leave when wave thins out.
  // Any lane death implies the queue counter passed rend, so popcount<64
  // means the queue is exhausted; gang mode (with full row succession) is
  // strictly better below A~50 (retire-rate model, p~0.16). ---
  while (true) {
    uint64_t msk = __ballot(have);
    if (__popcll(msk) <= GANGA) break;
    if (have) {
      // monotone watermark: re-poll only when the cache is insufficient
      if (wml < (uint32_t)(t + 2)) {
        uint32_t w_ = *(volatile uint32_t*)&wm;
        while (w_ < (uint32_t)(t + 2)) w_ = *(volatile uint32_t*)&wm;
        __threadfence_block();
        wml = w_;
      }
      uint4 ckn = chain[t + 1];

      float y0, y1, y2v, y3;
      bool alr = trial_eval(ck, r, lam1, lam2, lam3, sgi1, sgi2, sgi3,
                            sig1, sig2, sig3, sgi0, sig0, y0, y1, y2v, y3);

      ++t;
      if (alr || (t >= MAXT)) {
        // fused epilogue: qn-normalize + E^T + final store (q prefetched)
        store_final(out, r, cq0, cq1, cq2, cq3, y0, y1, y2v, y3);
        r = rn;
        cq0 = nq0; cq1 = nq1; cq2 = nq2; cq3 = nq3;
        int li = (r < rend ? r : rend - 1) - rbeg;   // clamp: OOB lanes unused
        float4 A = rc4a[li], B = rc4b[li];
        sgi1 = A.x; sgi2 = A.y; sgi3 = A.z; sig1 = A.w;
        sig2 = B.x; sig3 = B.y; lam1 = B.z; lam2 = B.w;
        lam3 = rc1[li];
        t = 0;
        ck = ck0;
        have = (r < rend);
        rn = (int)atomicAdd(&next_row, 1u);   // pre-grab: iterations of slack
        if (rn < rend) {
          float4 qv = *reinterpret_cast<const float4*>(q + (size_t)rn * 4);
          nq0 = qv.x; nq1 = qv.y; nq2 = qv.z; nq3 = qv.w;
        }
      } else {
        ck = ckn;
      }
    }
  }

  // --- gang tail: NG rows x GW speculative offsets per wave-iteration.
  // Owners keep FULL row succession (r = rn; rn = atomicAdd) so held rn's
  // and any residual queue entries are consumed (R10-validated). ---
  uint64_t mask = __ballot(have);
  if (mask) {
    // chain must be fully published before direct chain[t] indexing
    if (wml < (uint32_t)(MAXT + 1)) {
      uint32_t w_ = *(volatile uint32_t*)&wm;
      while (w_ < (uint32_t)(MAXT + 1)) w_ = *(volatile uint32_t*)&wm;
      __threadfence_block();
      wml = w_;
    }
    while (mask) {
      int G = __popcll(mask); if (G > NG) G = NG;
      const int g = lane >> 2, k = lane & 3;
      const bool gact = (g < G);
      const int gidx = gact ? g : 0;
      // select the gidx-th set bit of mask (predicated walk; no arrays)
      uint64_t m = mask;
      int sl = __ffsll((unsigned long long)m) - 1;
#pragma unroll
      for (int i = 1; i < NG; ++i) {
        m &= m - 1;
        int b = __ffsll((unsigned long long)m) - 1;
        sl = (i <= gidx && b >= 0) ? b : sl;
      }
      int rg = __shfl(r, sl, 64);
      int tg = __shfl(t, sl, 64);
      int li = rg - rbeg;
      float4 A = rc4a[li], B = rc4b[li];
      float G1 = A.x, G2 = A.y, G3 = A.z, S1 = A.w;
      float S2 = B.x, S3 = B.y, L1 = B.z, L2 = B.w;
      float L3 = rc1[li];
      int ts = tg + k;                        // speculative trial index
      int tsc = ts < (MAXT - 1) ? ts : (MAXT - 1);
      uint4 cks = chain[tsc];
      float y0, y1, y2v, y3;
      bool alr = trial_eval(cks, rg, L1, L2, L3, G1, G2, G3,
                            S1, S2, S3, sgi0, sig0, y0, y1, y2v, y3);
      // forced accept at trial index MAXT-1 (sequential: post-inc t >= MAXT);
      // clamped lanes (ts > MAXT-1) can never win: an earlier forced k exists.
      // t += GW only happens when no accept in the window, so tg <= MAXT-1-GW
      // always holds on entry to the next window.
      bool acc = alr || (ts >= MAXT - 1);
      uint64_t bal = __ballot(acc && gact);
      uint64_t gb = (bal >> (g * GW)) & 0xfull;
      int kwin = gb ? (__ffsll((unsigned long long)gb) - 1) : GW;
      if (gact && k == kwin) {
        // winner computes the fused epilogue (q load is masked, L2-resident)
        float4 qv = *reinterpret_cast<const float4*>(q + (size_t)rg * 4);
        store_final(out, rg, qv.x, qv.y, qv.z, qv.w, y0, y1, y2v, y3);
      }
      // owner bookkeeping with full succession (the R9 fix)
      int myidx = __popcll(mask & ((1ull << lane) - 1ull));
      if (have && myidx < G) {
        uint64_t gbb = (bal >> (myidx * GW)) & 0xfull;
        if (gbb) {
          r = rn;
          t = 0;
          have = (r < rend);
          rn = (int)atomicAdd(&next_row, 1u);
        } else {
          t += GW;                 // GW rejected trials consumed
        }
      }
      mask = __ballot(have);
    }
  }
}

extern "C" void kernel_launch(void* const* d_in, const int* in_sizes, int n_in,
                              void* d_out, int out_size, void* d_ws, size_t ws_size,
                              hipStream_t stream) {
  const float* q = (const float*)d_in[0];
  const float* Z = (const float*)d_in[1];
  const int* seed = (const int*)d_in[2];
  float* out = (float*)d_out;
  int N = in_sizes[0] / 4;

  int nb = GRID;
  int C = (N + nb - 1) / nb;        // rows per block (contiguous chunk)
  if (C > CMAX) {                   // keep LDS row table in bounds
    nb = (N + CMAX - 1) / CMAX;
    C = (N + nb - 1) / nb;
  }
  campose_kernel<<<nb, NT, 0, stream>>>(q, Z, out, seed, N, C);
}

// Round 11
// 155.698 us; speedup vs baseline: 1.0303x; 1.0303x over previous
//
#include <hip/hip_runtime.h>
#include <cstdint>

// CamPoseNet: bit-faithful JAX threefry replication (validated rounds 1-4).
// Round 16: revert to the R13-validated best (96.5-99.4us dispatch). The
// 11-round ledger: time tracks issued VALU instructions at a fixed ~66%-busy
// effective issue rate, invariant to occupancy (R11), forced ILP (R7), and
// instruction re-encoding (R12/R15 packed-fp32: 0 to -18%). All real wins
// were instruction REMOVAL (R8 hoist+log-merge, R10 gang tail, R13 packing);
// those are exhausted: threefry (~350 instrs/trial) is bit-exactness-mandated
// int work with no packed u32 path on CDNA4, erfinv/log DAGs are mandated,
// and the accept/normalize scaffolding is minimal. Floor arithmetic: 129K
// wave-iters x ~1400 SIMD-cyc / 1024 SIMDs ~ 73us @ 100% issue; measured
// ~97us @ 66% busy. This file is the empirical-best R13 source, unchanged.
// All float ops on the accept-decision path use __f*_rn intrinsics (no FMA
// contraction) - matches XLA:CPU strict mul/add. Do not alter any arithmetic.

#define DEVI __device__ __forceinline__
#define MAXT 96
#define GRID 512
#define NT 256
#define CMAX 2048
#define GANGA 56
#define NG 16
#define GW 4

DEVI uint32_t rotl32(uint32_t v, int s) { return (v << s) | (v >> (32 - s)); }

// Threefry-2x32, 20 rounds (jax._src.prng.threefry2x32) - scalar form,
// used only by the chain producer.
DEVI void tf2x32(uint32_t k0, uint32_t k1, uint32_t x0, uint32_t x1,
                 uint32_t& o0, uint32_t& o1) {
  const uint32_t kx = k0 ^ k1 ^ 0x1BD11BDAu;
  x0 += k0; x1 += k1;
#define TFR(r) x0 += x1; x1 = rotl32(x1, (r)); x1 ^= x0;
  TFR(13) TFR(15) TFR(26) TFR(6)
  x0 += k1; x1 += kx + 1u;
  TFR(17) TFR(29) TFR(16) TFR(24)
  x0 += kx; x1 += k0 + 2u;
  TFR(13) TFR(15) TFR(26) TFR(6)
  x0 += k0; x1 += k1 + 3u;
  TFR(17) TFR(29) TFR(16) TFR(24)
  x0 += k1; x1 += kx + 4u;
  TFR(13) TFR(15) TFR(26) TFR(6)
  x0 += kx; x1 += k0 + 5u;
#undef TFR
  o0 = x0; o1 = x1;
}

// 5-way interleaved threefry: streams 0-3 use key (ck.x,ck.y) with counters
// base+j; stream 4 uses key (ck.z,ck.w) with counter ctr. Identical per-stream
// op sequence to tf2x32 (only instruction interleaving differs).
DEVI void tf_round5(uint32_t x0[5], uint32_t x1[5], int rr) {
#pragma unroll
  for (int j = 0; j < 5; ++j) {
    x0[j] += x1[j];
    x1[j] = rotl32(x1[j], rr);
    x1[j] ^= x0[j];
  }
}
DEVI void tf_inj5(uint32_t x0[5], uint32_t x1[5],
                  const uint32_t* sa, const uint32_t* sb, uint32_t add) {
#pragma unroll
  for (int j = 0; j < 5; ++j) { x0[j] += sa[j]; x1[j] += sb[j] + add; }
}

DEVI float u01_from_bits(uint32_t bits) {
  return __fsub_rn(__uint_as_float(0x3f800000u | (bits >> 9)), 1.0f);
}

DEVI void trial5(uint4 ck, uint32_t base, uint32_t ctr, float u[5]) {
  uint32_t s0[5], s1[5], s2k[5], x0[5], x1[5];
#pragma unroll
  for (int j = 0; j < 5; ++j) {
    uint32_t k0 = (j < 4) ? ck.x : ck.z;
    uint32_t k1 = (j < 4) ? ck.y : ck.w;
    s0[j] = k0; s1[j] = k1; s2k[j] = k0 ^ k1 ^ 0x1BD11BDAu;
    uint32_t c = (j < 4) ? (base + (uint32_t)j) : ctr;
    x0[j] = k0;        // 0 + k0
    x1[j] = c + k1;    // counter + k1
  }
  tf_round5(x0, x1, 13); tf_round5(x0, x1, 15);
  tf_round5(x0, x1, 26); tf_round5(x0, x1, 6);
  tf_inj5(x0, x1, s1, s2k, 1u);
  tf_round5(x0, x1, 17); tf_round5(x0, x1, 29);
  tf_round5(x0, x1, 16); tf_round5(x0, x1, 24);
  tf_inj5(x0, x1, s2k, s0, 2u);
  tf_round5(x0, x1, 13); tf_round5(x0, x1, 15);
  tf_round5(x0, x1, 26); tf_round5(x0, x1, 6);
  tf_inj5(x0, x1, s0, s1, 3u);
  tf_round5(x0, x1, 17); tf_round5(x0, x1, 29);
  tf_round5(x0, x1, 16); tf_round5(x0, x1, 24);
  tf_inj5(x0, x1, s1, s2k, 4u);
  tf_round5(x0, x1, 13); tf_round5(x0, x1, 15);
  tf_round5(x0, x1, 26); tf_round5(x0, x1, 6);
  tf_inj5(x0, x1, s2k, s0, 5u);
#pragma unroll
  for (int j = 0; j < 5; ++j) u[j] = u01_from_bits(x0[j] ^ x1[j]);
}

// K-way interleaved XLA:CPU Cephes-style f32 log, strict mul/add.
// Per-lane op sequence identical to the scalar version (selects pick the
// same values the branchy form computes). x > 0, normal.
template <int K>
DEVI void xla_logf_pos_k(const float* xf, float* out) {
  float e[K], m[K], z[K], y[K];
#pragma unroll
  for (int j = 0; j < K; ++j) {
    uint32_t bits = __float_as_uint(xf[j]);
    e[j] = (float)((int)(bits >> 23) - 126);
    m[j] = __uint_as_float((bits & 0x007fffffu) | 0x3f000000u);  // [0.5,1)
    bool mc = m[j] < 0.70710678118654752440f;
    float e_lo = __fsub_rn(e[j], 1.0f);
    float m_lo = __fadd_rn(__fsub_rn(m[j], 1.0f), m[j]);
    float m_hi = __fsub_rn(m[j], 1.0f);
    e[j] = mc ? e_lo : e[j];
    m[j] = mc ? m_lo : m_hi;
    z[j] = __fmul_rn(m[j], m[j]);
    y[j] = 7.0376836292e-2f;
  }
  const float LC[8] = {-1.1514610310e-1f,  1.1676998740e-1f,
                       -1.2420140846e-1f,  1.4249322787e-1f,
                       -1.6668057665e-1f,  2.0000714765e-1f,
                       -2.4999993993e-1f,  3.3333331174e-1f};
#pragma unroll
  for (int s = 0; s < 8; ++s)
#pragma unroll
    for (int j = 0; j < K; ++j)
      y[j] = __fadd_rn(__fmul_rn(y[j], m[j]), LC[s]);
#pragma unroll
  for (int j = 0; j < K; ++j) {
    float t = __fmul_rn(__fmul_rn(y[j], m[j]), z[j]);
    t = __fadd_rn(t, __fmul_rn(e[j], -2.12194440e-4f));
    t = __fsub_rn(t, __fmul_rn(z[j], 0.5f));
    float r = __fadd_rn(m[j], t);
    out[j] = __fadd_rn(r, __fmul_rn(e[j], 0.693359375f));
  }
}

// 4-way interleaved XLA ErfInv32 + the uniform's log folded in as a 5th
// stream of the shared log (uu's log op-sequence identical to scalar form).
DEVI void xla_erfinv4_logu(const float* xin, float uu, float* res,
                           float& lg_uu) {
  float v[4], vp1[5], big[5], w[4], q[4], p[4];
  bool c[4];
#pragma unroll
  for (int j = 0; j < 4; ++j) {
    v[j] = -__fmul_rn(xin[j], xin[j]);
    vp1[j] = __fadd_rn(v[j], 1.0f);
  }
  vp1[4] = uu;                      // independent 5th log stream
  xla_logf_pos_k<5>(vp1, big);
  lg_uu = big[4];
#pragma unroll
  for (int j = 0; j < 4; ++j) {
    float small = __fmul_rn(__fadd_rn(__fmul_rn(-0.5f, v[j]), 1.0f), v[j]);
    float l1p = (fabsf(v[j]) < 1e-4f) ? small : big[j];
    w[j] = -l1p;
    c[j] = (w[j] < 5.0f);
    float qc = __fsub_rn(w[j], 2.5f);
    float qr = __fsub_rn(sqrtf(w[j]), 3.0f);
    q[j] = c[j] ? qc : qr;
    p[j] = c[j] ? 2.81022636e-08f : -0.000200214257f;
  }
  const float CF[8] = { 3.43273939e-07f, -3.5233877e-06f, -4.39150654e-06f,
                        0.00021858087f,  -0.00125372503f, -0.00417768164f,
                        0.246640727f,     1.50140941f};
  const float CR[8] = { 0.000100950558f,  0.00134934322f, -0.00367342844f,
                        0.00573950773f,  -0.0076224613f,   0.00943887047f,
                        1.00167406f,      2.83297682f};
#pragma unroll
  for (int s = 0; s < 8; ++s)
#pragma unroll
    for (int j = 0; j < 4; ++j)
      p[j] = __fadd_rn(__fmul_rn(p[j], q[j]), c[j] ? CF[s] : CR[s]);
#pragma unroll
  for (int j = 0; j < 4; ++j) res[j] = __fmul_rn(p[j], xin[j]);
}

// One full rejection trial for row r with subkeys ck: pure function of
// (r, ck, row constants). Returns the lu<lr accept test; y out by ref.
// EXACT op sequence of the validated R8/R10 loop body (shared by normal +
// gang paths -> bit-exact).
DEVI bool trial_eval(uint4 ck, int r,
                     float lam1, float lam2, float lam3,
                     float sgi1, float sgi2, float sgi3,
                     float sig1, float sig2, float sig3,
                     float sgi0, float sig0,
                     float& ry0, float& ry1, float& ry2, float& ry3) {
  const uint32_t base = ((uint32_t)r) * 4u;

  // 5 interleaved threefry streams: 4 normals + 1 uniform
  float u5[5];
  trial5(ck, base, (uint32_t)r, u5);
  float uu = u5[4];

  float xin[4];
#pragma unroll
  for (int j = 0; j < 4; ++j) {
    float x = __fadd_rn(__fmul_rn(u5[j], 2.0f), -0.99999994f);
    xin[j] = fmaxf(-0.99999994f, x);
  }
  float er[4], lg_uu;
  xla_erfinv4_logu(xin, uu, er, lg_uu);   // log(uu) rides the 4-way log

  float y0 = __fmul_rn(__fmul_rn(1.41421356237309504880f, er[0]), sig0);
  float y1 = __fmul_rn(__fmul_rn(1.41421356237309504880f, er[1]), sig1);
  float y2v = __fmul_rn(__fmul_rn(1.41421356237309504880f, er[2]), sig2);
  float y3 = __fmul_rn(__fmul_rn(1.41421356237309504880f, er[3]), sig3);

  // normalize (sequential reduce order)
  float n2 = __fmul_rn(y0, y0);
  n2 = __fadd_rn(n2, __fmul_rn(y1, y1));
  n2 = __fadd_rn(n2, __fmul_rn(y2v, y2v));
  n2 = __fadd_rn(n2, __fmul_rn(y3, y3));
  float nr = sqrtf(n2);
  y0 = __fdiv_rn(y0, nr); y1 = __fdiv_rn(y1, nr);
  y2v = __fdiv_rn(y2v, nr); y3 = __fdiv_rn(y3, nr);

  float s0q = __fmul_rn(y0, y0), s1q = __fmul_rn(y1, y1);
  float s2q = __fmul_rn(y2v, y2v), s3q = __fmul_rn(y3, y3);

  float s1v = __fmul_rn(s0q, 1e-6f);
  s1v = __fadd_rn(s1v, __fmul_rn(s1q, lam1));
  s1v = __fadd_rn(s1v, __fmul_rn(s2q, lam2));
  s1v = __fadd_rn(s1v, __fmul_rn(s3q, lam3));

  float s2v = __fmul_rn(s0q, sgi0);
  s2v = __fadd_rn(s2v, __fmul_rn(s1q, sgi1));
  s2v = __fadd_rn(s2v, __fmul_rn(s2q, sgi2));
  s2v = __fadd_rn(s2v, __fmul_rn(s3q, sgi3));

  float lg_s2[1];
  xla_logf_pos_k<1>(&s2v, lg_s2);

  float lr = __fsub_rn(-s1v, 2.7725887298583984f);  // 2*f32(ln 4)
  lr = __fadd_rn(lr, 1.5f);
  lr = __fadd_rn(lr, __fmul_rn(2.0f, lg_s2[0]));

  float lu = (uu > 0.0f) ? lg_uu : -__builtin_inff();

  ry0 = y0; ry1 = y1; ry2 = y2v; ry3 = y3;
  return (lu < lr);
}

// ---------------------------------------------------------------------------
__global__ __launch_bounds__(256, 2) void campose_kernel(
    const float* __restrict__ q, const float* __restrict__ Z,
    float* __restrict__ out, const int* __restrict__ seedp, int N, int C) {
  __shared__ uint4 chain[MAXT + 1];
  // Packed row constants (bit-exact values; only the load shape changed):
  //   rc4a[i] = {sgi1, sgi2, sgi3, sig1}
  //   rc4b[i] = {sig2, sig3, lam1, lam2}
  //   rc1[i]  = lam3
  __shared__ float4 rc4a[CMAX];
  __shared__ float4 rc4b[CMAX];
  __shared__ float rc1[CMAX];
  __shared__ uint32_t next_row;
  __shared__ uint32_t wm;   // watermark: # of published chain entries

  const int tid = threadIdx.x;
  const int lane = tid & 63;
  const int rbeg = blockIdx.x * C;
  const int rend = min(N, rbeg + C);
  const int crows = rend - rbeg;
  if (tid == 0) { next_row = (uint32_t)(rbeg + 192); wm = 0u; }

  // --- prepass: row constants (dense, high-ILP; values bit-identical to the
  // per-accept recompute they replace) ---
  for (int i = tid; i < crows; i += NT) {
    float z0 = Z[(size_t)(rbeg + i) * 3 + 0];
    float z1 = Z[(size_t)(rbeg + i) * 3 + 1];
    float z2 = Z[(size_t)(rbeg + i) * 3 + 2];
    float l1 = -z0, l2 = -z1, l3 = -z2;
    float g1 = __fadd_rn(1.0f, __fmul_rn(2.0f, l1));
    float g2 = __fadd_rn(1.0f, __fmul_rn(2.0f, l2));
    float g3 = __fadd_rn(1.0f, __fmul_rn(2.0f, l3));
    float s1_ = sqrtf(__fdiv_rn(1.0f, g1));
    float s2_ = sqrtf(__fdiv_rn(1.0f, g2));
    float s3_ = sqrtf(__fdiv_rn(1.0f, g3));
    rc4a[i] = make_float4(g1, g2, g3, s1_);
    rc4b[i] = make_float4(s2_, s3_, l1, l2);
    rc1[i] = l3;
  }
  __syncthreads();

  const int wave = tid >> 6;
  if (wave == 0) {
    // Producer: lanes 0-2 of wave 0 walk the split() chain; publish each
    // entry with a release watermark. Other waves consume concurrently.
    uint32_t ka = 0u, kb = (uint32_t)seedp[0];
    uint32_t x1i = (lane == 2) ? 0u : (uint32_t)(lane + 1);
    for (int t = 0; t < MAXT; ++t) {
      uint32_t o0 = 0u, o1 = 0u;
      if (lane < 3) tf2x32(ka, kb, 0u, x1i, o0, o1);
      uint32_t s1a = __shfl(o0, 0, 64), s1b = __shfl(o1, 0, 64);
      uint32_t s2a = __shfl(o0, 1, 64), s2b = __shfl(o1, 1, 64);
      if (lane == 0) chain[t] = make_uint4(s1a, s1b, s2a, s2b);
      ka = __shfl(o0, 2, 64); kb = __shfl(o1, 2, 64);
      __threadfence_block();
      if (lane == 0) *(volatile uint32_t*)&wm = (uint32_t)(t + 1);
    }
    if (lane == 0) chain[MAXT] = make_uint4(0u, 0u, 0u, 0u);  // prefetch pad
    __threadfence_block();
    if (lane == 0) *(volatile uint32_t*)&wm = (uint32_t)(MAXT + 1);
  }

  const float sgi0 = __fadd_rn(1.0f, __fmul_rn(2.0f, 1e-6f));
  const float sig0 = sqrtf(__fdiv_rn(1.0f, sgi0));

  // --- per-lane row state: current row r + pre-grabbed next row rn ---
  int r, rn;
  if (wave == 0) {
    r  = (int)atomicAdd(&next_row, 1u);   // producer wave joins late; queue
    rn = (int)atomicAdd(&next_row, 1u);   // auto-balances
  } else {
    r  = rbeg + (tid - 64);               // static first 192 rows
    rn = (int)atomicAdd(&next_row, 1u);
  }
  bool have = (r < rend);
  float lam1 = 0, lam2 = 0, lam3 = 0;
  float sgi1 = 1, sgi2 = 1, sgi3 = 1;
  float sig1 = 1, sig2 = 1, sig3 = 1;
  if (have) {
    int li = r - rbeg;
    float4 A = rc4a[li], B = rc4b[li];
    sgi1 = A.x; sgi2 = A.y; sgi3 = A.z; sig1 = A.w;
    sig2 = B.x; sig3 = B.y; lam1 = B.z; lam2 = B.w;
    lam3 = rc1[li];
  }

  // wait for chain[0]; cache it (reused at every accept)
  uint32_t wml = *(volatile uint32_t*)&wm;
  while (wml < 1u) wml = *(volatile uint32_t*)&wm;
  __threadfence_block();
  const uint4 ck0 = chain[0];
  uint4 ck = ck0;
  int t = 0;

  // --- normal phase: per-lane async rows; leave when wave thins out.
  // Any lane death implies the queue counter passed rend, so popcount<64
  // means the queue is exhausted; gang mode (with full row succession) is
  // strictly better below A~50 (retire-rate model, p~0.16). ---
  while (true) {
    uint64_t msk = __ballot(have);
    if (__popcll(msk) <= GANGA) break;
    if (have) {
      // monotone watermark: re-poll only when the cache is insufficient
      if (wml < (uint32_t)(t + 2)) {
        uint32_t w_ = *(volatile uint32_t*)&wm;
        while (w_ < (uint32_t)(t + 2)) w_ = *(volatile uint32_t*)&wm;
        __threadfence_block();
        wml = w_;
      }
      uint4 ckn = chain[t + 1];

      float y0, y1, y2v, y3;
      bool alr = trial_eval(ck, r, lam1, lam2, lam3, sgi1, sgi2, sgi3,
                            sig1, sig2, sig3, sgi0, sig0, y0, y1, y2v, y3);

      ++t;
      if (alr || (t >= MAXT)) {
        // lean accept path: store y; E^T deferred to pass 2
        *reinterpret_cast<float4*>(out + (size_t)r * 4) =
            make_float4(y0, y1, y2v, y3);
        r = rn;
        int li = (r < rend ? r : rend - 1) - rbeg;   // clamp: OOB lanes unused
        float4 A = rc4a[li], B = rc4b[li];
        sgi1 = A.x; sgi2 = A.y; sgi3 = A.z; sig1 = A.w;
        sig2 = B.x; sig3 = B.y; lam1 = B.z; lam2 = B.w;
        lam3 = rc1[li];
        t = 0;
        ck = ck0;
        have = (r < rend);
        rn = (int)atomicAdd(&next_row, 1u);   // pre-grab: iterations of slack
      } else {
        ck = ckn;
      }
    }
  }

  // --- gang tail: NG rows x GW speculative offsets per wave-iteration.
  // Owners keep FULL row succession (r = rn; rn = atomicAdd) so held rn's
  // and any residual queue entries are consumed (R10-validated). ---
  uint64_t mask = __ballot(have);
  if (mask) {
    // chain must be fully published before direct chain[t] indexing
    if (wml < (uint32_t)(MAXT + 1)) {
      uint32_t w_ = *(volatile uint32_t*)&wm;
      while (w_ < (uint32_t)(MAXT + 1)) w_ = *(volatile uint32_t*)&wm;
      __threadfence_block();
      wml = w_;
    }
    while (mask) {
      int G = __popcll(mask); if (G > NG) G = NG;
      const int g = lane >> 2, k = lane & 3;
      const bool gact = (g < G);
      const int gidx = gact ? g : 0;
      // select the gidx-th set bit of mask (predicated walk; no arrays)
      uint64_t m = mask;
      int sl = __ffsll((unsigned long long)m) - 1;
#pragma unroll
      for (int i = 1; i < NG; ++i) {
        m &= m - 1;
        int b = __ffsll((unsigned long long)m) - 1;
        sl = (i <= gidx && b >= 0) ? b : sl;
      }
      int rg = __shfl(r, sl, 64);
      int tg = __shfl(t, sl, 64);
      int li = rg - rbeg;
      float4 A = rc4a[li], B = rc4b[li];
      float G1 = A.x, G2 = A.y, G3 = A.z, S1 = A.w;
      float S2 = B.x, S3 = B.y, L1 = B.z, L2 = B.w;
      float L3 = rc1[li];
      int ts = tg + k;                        // speculative trial index
      int tsc = ts < (MAXT - 1) ? ts : (MAXT - 1);
      uint4 cks = chain[tsc];
      float y0, y1, y2v, y3;
      bool alr = trial_eval(cks, rg, L1, L2, L3, G1, G2, G3,
                            S1, S2, S3, sgi0, sig0, y0, y1, y2v, y3);
      // forced accept at trial index MAXT-1 (sequential: post-inc t >= MAXT);
      // clamped lanes (ts > MAXT-1) can never win: an earlier forced k exists.
      // t += GW only happens when no accept in the window, so tg <= MAXT-1-GW
      // always holds on entry to the next window.
      bool acc = alr || (ts >= MAXT - 1);
      uint64_t bal = __ballot(acc && gact);
      uint64_t gb = (bal >> (g * GW)) & 0xfull;
      int kwin = gb ? (__ffsll((unsigned long long)gb) - 1) : GW;
      if (gact && k == kwin) {
        *reinterpret_cast<float4*>(out + (size_t)rg * 4) =
            make_float4(y0, y1, y2v, y3);
      }
      // owner bookkeeping with full succession (the R9 fix)
      int myidx = __popcll(mask & ((1ull << lane) - 1ull));
      if (have && myidx < G) {
        uint64_t gbb = (bal >> (myidx * GW)) & 0xfull;
        if (gbb) {
          r = rn;
          t = 0;
          have = (r < rend);
          rn = (int)atomicAdd(&next_row, 1u);
        } else {
          t += GW;                 // GW rejected trials consumed
        }
      }
      mask = __ballot(have);
    }
  }

  // --- pass 2: apply E^T over this block's chunk (coalesced) ---
  __syncthreads();   // all y-stores visible block-wide
  for (int i = rbeg + tid; i < rend; i += NT) {
    float4 yv = *reinterpret_cast<const float4*>(out + (size_t)i * 4);
    float4 qv = *reinterpret_cast<const float4*>(q + (size_t)i * 4);
    float a = qv.x, b = qv.y, c = qv.z, d = qv.w;
    float qn2 = __fmul_rn(a, a);
    qn2 = __fadd_rn(qn2, __fmul_rn(b, b));
    qn2 = __fadd_rn(qn2, __fmul_rn(c, c));
    qn2 = __fadd_rn(qn2, __fmul_rn(d, d));
    float qnr = sqrtf(qn2);
    a = __fdiv_rn(a, qnr); b = __fdiv_rn(b, qnr);
    c = __fdiv_rn(c, qnr); d = __fdiv_rn(d, qnr);
    float y0 = yv.x, y1 = yv.y, y2v = yv.z, y3 = yv.w;
    float o0v = __fadd_rn(__fadd_rn(__fadd_rn(__fmul_rn(a, y0), __fmul_rn(b, y1)),
                                    __fmul_rn(c, y2v)), __fmul_rn(d, y3));
    float o1v = __fadd_rn(__fadd_rn(__fadd_rn(__fmul_rn(-b, y0), __fmul_rn(a, y1)),
                                    __fmul_rn(-d, y2v)), __fmul_rn(c, y3));
    float o2v = __fadd_rn(__fadd_rn(__fadd_rn(__fmul_rn(-c, y0), __fmul_rn(d, y1)),
                                    __fmul_rn(a, y2v)), __fmul_rn(-b, y3));
    float o3v = __fadd_rn(__fadd_rn(__fadd_rn(__fmul_rn(d, y0), __fmul_rn(c, y1)),
                                    __fmul_rn(-b, y2v)), __fmul_rn(-a, y3));
    *reinterpret_cast<float4*>(out + (size_t)i * 4) =
        make_float4(o0v, o1v, o2v, o3v);
  }
}

extern "C" void kernel_launch(void* const* d_in, const int* in_sizes, int n_in,
                              void* d_out, int out_size, void* d_ws, size_t ws_size,
                              hipStream_t stream) {
  const float* q = (const float*)d_in[0];
  const float* Z = (const float*)d_in[1];
  const int* seed = (const int*)d_in[2];
  float* out = (float*)d_out;
  int N = in_sizes[0] / 4;

  int nb = GRID;
  int C = (N + nb - 1) / nb;        // rows per block (contiguous chunk)
  if (C > CMAX) {                   // keep LDS row table in bounds
    nb = (N + CMAX - 1) / CMAX;
    C = (N + nb - 1) / nb;
  }
  campose_kernel<<<nb, NT, 0, stream>>>(q, Z, out, seed, N, C);
}